// Round 2
// baseline (279.398 us; speedup 1.0000x reference)
//
#include <hip/hip_runtime.h>
#include <math.h>

#define VIEWS 512
#define DETS  512

typedef float f32x4 __attribute__((ext_vector_type(4)));
typedef float f32x2 __attribute__((ext_vector_type(2)));

// derived constants (double, folded at compile time)
constexpr double S2R_D    = 5.95;
constexpr double D2R_D    = 4.906;
constexpr double DDET_D   = 0.0072;
constexpr double VIRDET_D = DDET_D * S2R_D / (S2R_D + D2R_D);
constexpr double DANG_D   = 2.0 * 3.14159265358979323846 / (double)VIEWS;
constexpr double DIMG_D   = 0.006641;

// ---------------------------------------------------------------------------
// Fused kernel: one block per view, 512 threads (8 waves) -> 4 waves/SIMD.
//   phase 0: zero pads, stage filter taps + proj*w rows (both batches) in LDS
//   phase 1: ramp filter (even-tap trimmed scheme), waves 0-3 only (the
//            filter is LDS-unit-bound per CU; more waves wouldn't help) ->
//            zero-padded interleaved LDS row pair rows01[det -128..639][b]
//   phase 2: backprojection of the full 2x256x256 slab with all 8 waves.
//            Zero-padding removes all bounds masks/clamps:
//            t+128 in [3.0, 763.5], so idx in [3,763], idx+1 <= 764 < 768.
// ---------------------------------------------------------------------------
__global__ __launch_bounds__(512, 4) void fbp_fused_kernel(
    const float* __restrict__ proj, const float* __restrict__ wq,
    const float* __restrict__ filt, float* __restrict__ out)
{
    __shared__ __align__(16) float pwpad[2][1536];   // padded proj*w rows
    __shared__ __align__(16) float sfe[520];         // even-index taps
    __shared__ __align__(16) float rows01[1536];     // {r0,r1} interleaved, det -128..639

    const int tid = threadIdx.x;
    const int v   = blockIdx.x;                      // view

    const float beta = (float)DANG_D * (float)v;
    const float cb = cosf(beta);
    const float sb = sinf(beta);

    {   // phase 0a: zero-init pads + stage taps (all 512 threads)
        const f32x4 z = {0.f, 0.f, 0.f, 0.f};
        f32x4* pz = (f32x4*)&pwpad[0][0];            // 768 f32x4
        pz[tid] = z;                                 // tid < 512
        if (tid < 256) pz[512 + tid] = z;
        f32x4* rz = (f32x4*)rows01;                  // 384 f32x4
        if (tid < 384) rz[tid] = z;
        for (int i = tid; i < 520; i += 512)
            sfe[i] = (i < 512) ? filt[2*i] : 0.0f;
    }
    __syncthreads();

    if (tid < 256) {   // phase 0b: stage proj rows * w (rows = {v, 512+v})
        const int rl  = tid >> 7;
        const int t2  = tid & 127;
        const int row = rl * VIEWS + v;              // batch-major row index
        const f32x4 p4 = *(const f32x4*)(proj + ((size_t)row << 9) + 4*t2);
        const f32x4 w4 = *(const f32x4*)(wq + 4*t2);
        pwpad[rl][511 + 4*t2 + 0] = p4.x * w4.x;
        pwpad[rl][511 + 4*t2 + 1] = p4.y * w4.y;
        pwpad[rl][511 + 4*t2 + 2] = p4.z * w4.z;
        pwpad[rl][511 + 4*t2 + 3] = p4.w * w4.w;
    }
    __syncthreads();

    const int lane = tid & 63;
    const int warp = tid >> 6;                       // 0..7

    if (warp < 4) {  // phase 1: ramp filter. warp -> (row = warp>>1, half = warp&1)
        const int rl2 = warp >> 1;
        const int wv  = warp & 1;
        const int d0  = 256*wv + 4*lane;             // first of 4 outputs
        const float* P = &pwpad[rl2][0];
        const int e_lo = wv ? 0 : 124;               // trimmed even-tap range
        const int G    = wv ? 48 : 49;
        const float c0 = filt[511];                  // center tap
        float a0=0.f, a1=0.f, a2=0.f, a3=0.f;
        for (int g = 0; g < G; ++g) {
            const int e0 = e_lo + 8*g;
            const f32x4 S0 = *(const f32x4*)&sfe[e0];      // wave-uniform broadcast
            const f32x4 S1 = *(const f32x4*)&sfe[e0 + 4];
            const float* Pb = P + d0 + 2*e0;               // 16B aligned
            const f32x4 q0 = *(const f32x4*)(Pb + 0);
            const f32x4 q1 = *(const f32x4*)(Pb + 4);
            const f32x4 q2 = *(const f32x4*)(Pb + 8);
            const f32x4 q3 = *(const f32x4*)(Pb + 12);
            const f32x4 q4 = *(const f32x4*)(Pb + 16);
            const float p[20] = {q0.x,q0.y,q0.z,q0.w, q1.x,q1.y,q1.z,q1.w,
                                 q2.x,q2.y,q2.z,q2.w, q3.x,q3.y,q3.z,q3.w,
                                 q4.x,q4.y,q4.z,q4.w};
            const float s[8]  = {S0.x,S0.y,S0.z,S0.w, S1.x,S1.y,S1.z,S1.w};
            #pragma unroll
            for (int j = 0; j < 8; ++j) {
                a0 = fmaf(p[2*j + 0], s[j], a0);
                a1 = fmaf(p[2*j + 1], s[j], a1);
                a2 = fmaf(p[2*j + 2], s[j], a2);
                a3 = fmaf(p[2*j + 3], s[j], a3);
            }
        }
        a0 = fmaf(P[511 + d0 + 0], c0, a0);
        a1 = fmaf(P[511 + d0 + 1], c0, a1);
        a2 = fmaf(P[511 + d0 + 2], c0, a2);
        a3 = fmaf(P[511 + d0 + 3], c0, a3);
        // write interleaved {row0[d], row1[d]} at det offset +128
        float* W = &rows01[((128 + d0) << 1) + rl2];
        W[0] = a0; W[2] = a1; W[4] = a2; W[6] = a3;
    }
    __syncthreads();

    {   // phase 2: backprojection, whole view slab; 8 waves, y = 8i + warp.
        const float D    = (float)DIMG_D;
        const float Kf   = (float)(S2R_D / VIRDET_D);    // 5.95/VIRDET
        const int   xi   = 4*lane;
        const float xs0  = ((float)xi - 127.5f) * D;
        const float xc0  = xs0 * cb;
        const float xsbK = (xs0 * sb) * Kf;
        const float dcb  = D * cb;
        const float dsbK = (D * sb) * Kf;
        const float d0c  = 5.95f - xc0;                  // per-lane
        const float ysw  = (127.5f - (float)warp) * D;   // wave-uniform
        const f32x2* R2  = (const f32x2*)rows01;
        f32x4* o0p = (f32x4*)(out + ((size_t)v << 16));
        f32x4* o1p = o0p + 8388608u;                     // batch 1

        #pragma unroll 2
        for (int i = 0; i < 32; ++i) {
            const float ys  = fmaf((float)i, -8.0f*D, ysw);  // wave-uniform
            const float ysb = ys * sb;
            const float ycb = ys * cb;
            const float dbase = d0c - ysb;                // den_j = dbase - j*dcb
            const float nbase = fmaf(Kf, ycb, -xsbK);     // num'_j = nbase - j*dsbK
            f32x4 o0, o1;
            #pragma unroll
            for (int j = 0; j < 4; ++j) {
                const float jf  = (float)j;
                const float den = fmaf(jf, -dcb,  dbase);
                const float num = fmaf(jf, -dsbK, nbase);
                float inv = __builtin_amdgcn_rcpf(den);
                inv = inv * fmaf(-den, inv, 2.0f);        // 1 Newton step
                const float wgt = 35.4025f * (inv * inv); // (5.95/den)^2
                const float t   = fmaf(num, inv, 383.5f); // 255.5 + 128 pad shift
                const float ft  = floorf(t);
                const float fr  = t - ft;
                const int   idx = (int)ft;                // in [3, 763]
                const f32x2 ab  = R2[idx];                // {r0[i0], r1[i0]}
                const f32x2 cd  = R2[idx + 1];            // {r0[i1], r1[i1]}
                o0[j] = wgt * fmaf(fr, cd.x - ab.x, ab.x);
                o1[j] = wgt * fmaf(fr, cd.y - ab.y, ab.y);
            }
            const int y = 8*i + warp;
            const size_t p4i = ((size_t)y << 6) + (size_t)lane;
            __builtin_nontemporal_store(o0, o0p + p4i);
            __builtin_nontemporal_store(o1, o1p + p4i);
        }
    }
}

extern "C" void kernel_launch(void* const* d_in, const int* in_sizes, int n_in,
                              void* d_out, int out_size, void* d_ws, size_t ws_size,
                              hipStream_t stream) {
    const float* proj = (const float*)d_in[0];   // (2,1,512,512)
    const float* wq   = (const float*)d_in[1];   // (512,)
    const float* filt = (const float*)d_in[2];   // (1023,)
    float* out = (float*)d_out;                  // (2,512,256,256)
    (void)in_sizes; (void)n_in; (void)out_size; (void)d_ws; (void)ws_size;

    hipLaunchKernelGGL(fbp_fused_kernel, dim3(VIEWS), dim3(512), 0, stream,
                       proj, wq, filt, out);
}

// Round 3
// 278.550 us; speedup vs baseline: 1.0030x; 1.0030x over previous
//
#include <hip/hip_runtime.h>
#include <math.h>

#define VIEWS 512
#define DETS  512

typedef float f32x4 __attribute__((ext_vector_type(4)));

// derived constants (double, folded at compile time)
constexpr double S2R_D    = 5.95;
constexpr double D2R_D    = 4.906;
constexpr double DDET_D   = 0.0072;
constexpr double VIRDET_D = DDET_D * S2R_D / (S2R_D + D2R_D);
constexpr double DANG_D   = 2.0 * 3.14159265358979323846 / (double)VIEWS;
constexpr double DIMG_D   = 0.006641;

// ---------------------------------------------------------------------------
// Fused kernel: one block per view, 512 threads (8 waves).
//   phase 0: zero pads, stage filter taps + proj*w rows (both batches) in LDS
//   phase 1: ramp filter (even-tap trimmed scheme), waves 0-3 ->
//            TWO separate zero-padded f32 rows rowsP[b][det -128..639]
//   phase 2: backprojection, all 8 waves. x is INTERLEAVED across lanes
//            (x = lane + 64*j) so the lane-to-lane detector-bin stride is
//            ~1.4-2.2 banks -> gathers are ~conflict-free (the old blocked
//            mapping had an 11-17.6 bank stride -> 8..32-way conflicts).
//            Zero-padding removes all bounds masks/clamps:
//            t+128 in [3.0, 763.5], so idx in [3,763], idx+1 <= 764 < 768.
// ---------------------------------------------------------------------------
__global__ __launch_bounds__(512, 4) void fbp_fused_kernel(
    const float* __restrict__ proj, const float* __restrict__ wq,
    const float* __restrict__ filt, float* __restrict__ out)
{
    __shared__ __align__(16) float pwpad[2][1536];   // padded proj*w rows
    __shared__ __align__(16) float sfe[520];         // even-index taps
    __shared__ __align__(16) float rowsP[2][776];    // filtered rows, det -128..639 (+pad)

    const int tid = threadIdx.x;
    const int v   = blockIdx.x;                      // view

    const float beta = (float)DANG_D * (float)v;
    const float cb = cosf(beta);
    const float sb = sinf(beta);

    {   // phase 0a: zero-init pads + stage taps (all 512 threads)
        const f32x4 z = {0.f, 0.f, 0.f, 0.f};
        f32x4* pz = (f32x4*)&pwpad[0][0];            // 768 f32x4
        pz[tid] = z;                                 // tid < 512
        if (tid < 256) pz[512 + tid] = z;
        f32x4* rz = (f32x4*)&rowsP[0][0];            // 388 f32x4
        if (tid < 388) rz[tid] = z;
        for (int i = tid; i < 520; i += 512)
            sfe[i] = (i < 512) ? filt[2*i] : 0.0f;
    }
    __syncthreads();

    if (tid < 256) {   // phase 0b: stage proj rows * w (rows = {v, 512+v})
        const int rl  = tid >> 7;
        const int t2  = tid & 127;
        const int row = rl * VIEWS + v;              // batch-major row index
        const f32x4 p4 = *(const f32x4*)(proj + ((size_t)row << 9) + 4*t2);
        const f32x4 w4 = *(const f32x4*)(wq + 4*t2);
        pwpad[rl][511 + 4*t2 + 0] = p4.x * w4.x;
        pwpad[rl][511 + 4*t2 + 1] = p4.y * w4.y;
        pwpad[rl][511 + 4*t2 + 2] = p4.z * w4.z;
        pwpad[rl][511 + 4*t2 + 3] = p4.w * w4.w;
    }
    __syncthreads();

    const int lane = tid & 63;
    const int warp = tid >> 6;                       // 0..7

    if (warp < 4) {  // phase 1: ramp filter. warp -> (row = warp>>1, half = warp&1)
        const int rl2 = warp >> 1;
        const int wv  = warp & 1;
        const int d0  = 256*wv + 4*lane;             // first of 4 outputs
        const float* P = &pwpad[rl2][0];
        const int e_lo = wv ? 0 : 124;               // trimmed even-tap range
        const int G    = wv ? 48 : 49;
        const float c0 = filt[511];                  // center tap
        float a0=0.f, a1=0.f, a2=0.f, a3=0.f;
        for (int g = 0; g < G; ++g) {
            const int e0 = e_lo + 8*g;
            const f32x4 S0 = *(const f32x4*)&sfe[e0];      // wave-uniform broadcast
            const f32x4 S1 = *(const f32x4*)&sfe[e0 + 4];
            const float* Pb = P + d0 + 2*e0;               // 16B aligned
            const f32x4 q0 = *(const f32x4*)(Pb + 0);
            const f32x4 q1 = *(const f32x4*)(Pb + 4);
            const f32x4 q2 = *(const f32x4*)(Pb + 8);
            const f32x4 q3 = *(const f32x4*)(Pb + 12);
            const f32x4 q4 = *(const f32x4*)(Pb + 16);
            const float p[20] = {q0.x,q0.y,q0.z,q0.w, q1.x,q1.y,q1.z,q1.w,
                                 q2.x,q2.y,q2.z,q2.w, q3.x,q3.y,q3.z,q3.w,
                                 q4.x,q4.y,q4.z,q4.w};
            const float s[8]  = {S0.x,S0.y,S0.z,S0.w, S1.x,S1.y,S1.z,S1.w};
            #pragma unroll
            for (int j = 0; j < 8; ++j) {
                a0 = fmaf(p[2*j + 0], s[j], a0);
                a1 = fmaf(p[2*j + 1], s[j], a1);
                a2 = fmaf(p[2*j + 2], s[j], a2);
                a3 = fmaf(p[2*j + 3], s[j], a3);
            }
        }
        a0 = fmaf(P[511 + d0 + 0], c0, a0);
        a1 = fmaf(P[511 + d0 + 1], c0, a1);
        a2 = fmaf(P[511 + d0 + 2], c0, a2);
        a3 = fmaf(P[511 + d0 + 3], c0, a3);
        // write filtered row segment (conflict-free ds_write_b128)
        f32x4 r4; r4.x = a0; r4.y = a1; r4.z = a2; r4.w = a3;
        *(f32x4*)&rowsP[rl2][128 + d0] = r4;
    }
    __syncthreads();

    {   // phase 2: backprojection; 8 waves, y = 8i + warp, x = lane + 64*j.
        const float D    = (float)DIMG_D;
        const float Kf   = (float)(S2R_D / VIRDET_D);    // 5.95/VIRDET
        const float xs0  = ((float)lane - 127.5f) * D;   // x step per lane = 1 px
        const float xc0  = xs0 * cb;
        const float xsbK = (xs0 * sb) * Kf;
        const float dcb64  = (64.0f * D) * cb;           // per-j steps (64 px)
        const float dsbK64 = (64.0f * D) * sb * Kf;
        const float d0c  = 5.95f - xc0;                  // per-lane
        const float* rA  = &rowsP[0][0];
        const float* rB  = &rowsP[1][0];
        float* outv = out + ((size_t)v << 16);
        float* outv1 = outv + ((size_t)VIEWS << 16);     // batch 1

        #pragma unroll 2
        for (int i = 0; i < 32; ++i) {
            const int   y   = 8*i + warp;                 // wave-uniform
            const float ys  = (127.5f - (float)y) * D;
            const float ysb = ys * sb;                    // scalar
            const float ycb = ys * cb;                    // scalar
            const float dbase = d0c - ysb;                // den_j = dbase - j*dcb64
            const float nbase = fmaf(Kf, ycb, -xsbK);     // num_j = nbase - j*dsbK64
            #pragma unroll
            for (int j = 0; j < 4; ++j) {
                const float jf  = (float)j;
                const float den = fmaf(jf, -dcb64,  dbase);
                const float num = fmaf(jf, -dsbK64, nbase);
                float inv = __builtin_amdgcn_rcpf(den);
                inv = inv * fmaf(-den, inv, 2.0f);        // 1 Newton step
                const float wgt = 35.4025f * (inv * inv); // (5.95/den)^2
                const float t   = fmaf(num, inv, 383.5f); // 255.5 + 128 pad shift
                const float ft  = floorf(t);
                const float fr  = t - ft;
                const int   idx = (int)ft;                // in [3, 763]
                const float a0 = rA[idx];                 // ds_read2_b32 pairs
                const float b0 = rA[idx + 1];
                const float a1 = rB[idx];
                const float b1 = rB[idx + 1];
                const float o0 = wgt * fmaf(fr, b0 - a0, a0);
                const float o1 = wgt * fmaf(fr, b1 - a1, a1);
                const size_t off = ((size_t)y << 8) + (size_t)(64*j + lane);
                __builtin_nontemporal_store(o0, outv  + off);
                __builtin_nontemporal_store(o1, outv1 + off);
            }
        }
    }
}

extern "C" void kernel_launch(void* const* d_in, const int* in_sizes, int n_in,
                              void* d_out, int out_size, void* d_ws, size_t ws_size,
                              hipStream_t stream) {
    const float* proj = (const float*)d_in[0];   // (2,1,512,512)
    const float* wq   = (const float*)d_in[1];   // (512,)
    const float* filt = (const float*)d_in[2];   // (1023,)
    float* out = (float*)d_out;                  // (2,512,256,256)
    (void)in_sizes; (void)n_in; (void)out_size; (void)d_ws; (void)ws_size;

    hipLaunchKernelGGL(fbp_fused_kernel, dim3(VIEWS), dim3(512), 0, stream,
                       proj, wq, filt, out);
}

// Round 4
// 278.221 us; speedup vs baseline: 1.0042x; 1.0012x over previous
//
#include <hip/hip_runtime.h>
#include <math.h>

#define VIEWS 512
#define DETS  512

typedef float f32x4 __attribute__((ext_vector_type(4)));

// derived constants (double, folded at compile time)
constexpr double S2R_D    = 5.95;
constexpr double D2R_D    = 4.906;
constexpr double DDET_D   = 0.0072;
constexpr double VIRDET_D = DDET_D * S2R_D / (S2R_D + D2R_D);
constexpr double DANG_D   = 2.0 * 3.14159265358979323846 / (double)VIEWS;
constexpr double DIMG_D   = 0.006641;

// ---------------------------------------------------------------------------
// Fused kernel: one block per view, 512 threads (8 waves).
//   phase 0: global loads issued FIRST (latency hides under LDS zero-init),
//            then zero pads + stage taps + proj*w rows in LDS.
//   phase 1: ramp filter (even-tap trimmed scheme), waves 0-3, with a
//            sliding-window carry (q4 of group g == q0 of group g+1) ->
//            197 instead of 245 ds_read_b128 per wave. Output: two separate
//            zero-padded f32 rows rowsP[b][det -128..639].
//   phase 2: backprojection, all 8 waves, x interleaved across lanes
//            (x = lane + 64*j) -> lane-to-lane det-bin stride ~1.4-2.2 banks,
//            gathers ~conflict-free. Zero-padding removes all bounds logic:
//            t+128 in [3.0, 763.5] -> idx in [3,763], idx+1 <= 764 < 776.
// ---------------------------------------------------------------------------
__global__ __launch_bounds__(512, 4) void fbp_fused_kernel(
    const float* __restrict__ proj, const float* __restrict__ wq,
    const float* __restrict__ filt, float* __restrict__ out)
{
    __shared__ __align__(16) float pwpad[2][1536];   // padded proj*w rows
    __shared__ __align__(16) float sfe[520];         // even-index taps
    __shared__ __align__(16) float rowsP[2][776];    // filtered rows, det -128..639 (+pad)

    const int tid = threadIdx.x;
    const int v   = blockIdx.x;                      // view

    const float beta = (float)DANG_D * (float)v;
    const float cb = cosf(beta);
    const float sb = sinf(beta);

    // ---- issue all global loads up-front (latency hides under zero-init)
    const float fe = filt[2 * tid];                  // tid in [0,511] -> filt[0..1022]
    f32x4 p4, w4;
    if (tid < 256) {
        const int rl  = tid >> 7;
        const int t2  = tid & 127;
        const int row = rl * VIEWS + v;              // batch-major row index
        p4 = *(const f32x4*)(proj + ((size_t)row << 9) + 4*t2);
        w4 = *(const f32x4*)(wq + 4*t2);
    }

    {   // phase 0a: zero-init pads (all 512 threads)
        const f32x4 z = {0.f, 0.f, 0.f, 0.f};
        f32x4* pz = (f32x4*)&pwpad[0][0];            // 768 f32x4
        pz[tid] = z;                                 // tid < 512
        if (tid < 256) pz[512 + tid] = z;
        f32x4* rz = (f32x4*)&rowsP[0][0];            // 388 f32x4
        if (tid < 388) rz[tid] = z;
        sfe[tid] = fe;
        if (tid < 8) sfe[512 + tid] = 0.0f;
    }
    __syncthreads();

    if (tid < 256) {   // phase 0b: stage proj rows * w into padded region
        const int rl  = tid >> 7;
        const int t2  = tid & 127;
        pwpad[rl][511 + 4*t2 + 0] = p4.x * w4.x;
        pwpad[rl][511 + 4*t2 + 1] = p4.y * w4.y;
        pwpad[rl][511 + 4*t2 + 2] = p4.z * w4.z;
        pwpad[rl][511 + 4*t2 + 3] = p4.w * w4.w;
    }
    __syncthreads();

    const int lane = tid & 63;
    const int warp = tid >> 6;                       // 0..7

    if (warp < 4) {  // phase 1: ramp filter. warp -> (row = warp>>1, half = warp&1)
        const int rl2 = warp >> 1;
        const int wv  = warp & 1;
        const int d0  = 256*wv + 4*lane;             // first of 4 outputs
        const float* P = &pwpad[rl2][0];
        const int e_lo = wv ? 0 : 124;               // trimmed even-tap range
        const int G    = wv ? 48 : 49;
        const float c0 = filt[511];                  // center tap (scalar)
        float a0=0.f, a1=0.f, a2=0.f, a3=0.f;
        const float* Pb = P + d0 + 2*e_lo;           // 16B aligned, advances 64B/group
        f32x4 qc = *(const f32x4*)Pb;                // carried window head
        for (int g = 0; g < G; ++g) {
            const int e0 = e_lo + 8*g;
            const f32x4 S0 = *(const f32x4*)&sfe[e0];      // wave-uniform broadcast
            const f32x4 S1 = *(const f32x4*)&sfe[e0 + 4];
            const f32x4 q1 = *(const f32x4*)(Pb + 4);
            const f32x4 q2 = *(const f32x4*)(Pb + 8);
            const f32x4 q3 = *(const f32x4*)(Pb + 12);
            const f32x4 q4 = *(const f32x4*)(Pb + 16);
            const float p[20] = {qc.x,qc.y,qc.z,qc.w, q1.x,q1.y,q1.z,q1.w,
                                 q2.x,q2.y,q2.z,q2.w, q3.x,q3.y,q3.z,q3.w,
                                 q4.x,q4.y,q4.z,q4.w};
            const float s[8]  = {S0.x,S0.y,S0.z,S0.w, S1.x,S1.y,S1.z,S1.w};
            #pragma unroll
            for (int j = 0; j < 8; ++j) {
                a0 = fmaf(p[2*j + 0], s[j], a0);
                a1 = fmaf(p[2*j + 1], s[j], a1);
                a2 = fmaf(p[2*j + 2], s[j], a2);
                a3 = fmaf(p[2*j + 3], s[j], a3);
            }
            qc = q4;
            Pb += 16;
        }
        a0 = fmaf(P[511 + d0 + 0], c0, a0);
        a1 = fmaf(P[511 + d0 + 1], c0, a1);
        a2 = fmaf(P[511 + d0 + 2], c0, a2);
        a3 = fmaf(P[511 + d0 + 3], c0, a3);
        // write filtered row segment (conflict-free ds_write_b128)
        f32x4 r4; r4.x = a0; r4.y = a1; r4.z = a2; r4.w = a3;
        *(f32x4*)&rowsP[rl2][128 + d0] = r4;
    }
    __syncthreads();

    {   // phase 2: backprojection; 8 waves, y = 8i + warp, x = lane + 64*j.
        const float D    = (float)DIMG_D;
        const float Kf   = (float)(S2R_D / VIRDET_D);    // 5.95/VIRDET
        const float xs0  = ((float)lane - 127.5f) * D;   // x step per lane = 1 px
        const float xc0  = xs0 * cb;
        const float xsbK = (xs0 * sb) * Kf;
        const float dcb64  = (64.0f * D) * cb;           // per-j steps (64 px)
        const float dsbK64 = (64.0f * D) * sb * Kf;
        const float d0c  = 5.95f - xc0;                  // per-lane
        const float* rA  = &rowsP[0][0];
        const float* rB  = &rowsP[1][0];
        float* outv  = out + ((size_t)v << 16);
        float* outv1 = outv + ((size_t)VIEWS << 16);     // batch 1

        #pragma unroll 2
        for (int i = 0; i < 32; ++i) {
            const int   y   = 8*i + warp;                 // wave-uniform
            const float ys  = (127.5f - (float)y) * D;
            const float ysb = ys * sb;                    // scalar
            const float ycb = ys * cb;                    // scalar
            const float dbase = d0c - ysb;                // den_j = dbase - j*dcb64
            const float nbase = fmaf(Kf, ycb, -xsbK);     // num_j = nbase - j*dsbK64
            #pragma unroll
            for (int j = 0; j < 4; ++j) {
                const float jf  = (float)j;
                const float den = fmaf(jf, -dcb64,  dbase);
                const float num = fmaf(jf, -dsbK64, nbase);
                float inv = __builtin_amdgcn_rcpf(den);
                inv = inv * fmaf(-den, inv, 2.0f);        // 1 Newton step
                const float wgt = 35.4025f * (inv * inv); // (5.95/den)^2
                const float t   = fmaf(num, inv, 383.5f); // 255.5 + 128 pad shift
                const float ft  = floorf(t);
                const float fr  = t - ft;
                const int   idx = (int)ft;                // in [3, 763]
                const float a0 = rA[idx];                 // ds_read2_b32 pairs
                const float b0 = rA[idx + 1];
                const float a1 = rB[idx];
                const float b1 = rB[idx + 1];
                const float o0 = wgt * fmaf(fr, b0 - a0, a0);
                const float o1 = wgt * fmaf(fr, b1 - a1, a1);
                const size_t off = ((size_t)y << 8) + (size_t)(64*j + lane);
                __builtin_nontemporal_store(o0, outv  + off);
                __builtin_nontemporal_store(o1, outv1 + off);
            }
        }
    }
}

extern "C" void kernel_launch(void* const* d_in, const int* in_sizes, int n_in,
                              void* d_out, int out_size, void* d_ws, size_t ws_size,
                              hipStream_t stream) {
    const float* proj = (const float*)d_in[0];   // (2,1,512,512)
    const float* wq   = (const float*)d_in[1];   // (512,)
    const float* filt = (const float*)d_in[2];   // (1023,)
    float* out = (float*)d_out;                  // (2,512,256,256)
    (void)in_sizes; (void)n_in; (void)out_size; (void)d_ws; (void)ws_size;

    hipLaunchKernelGGL(fbp_fused_kernel, dim3(VIEWS), dim3(512), 0, stream,
                       proj, wq, filt, out);
}